// Round 1
// baseline (806.161 us; speedup 1.0000x reference)
//
#include <hip/hip_runtime.h>
#include <math.h>

#define DXY   64
#define NN    4096      // 64*64
#define NB    2
#define PITCH 65        // LDS row pitch (bank-conflict pad)

__device__ __forceinline__ int lpos(int p) {
    return (p >> 6) * PITCH + (p & 63);
}

// ---------------- radix-4 DIF forward (output digit-reversed) ----------------
// es = element stride along transform axis, rs = stride between the 64 FFTs
__device__ void fft64_fwd(float* re, float* im, const float* twr, const float* twi,
                          int es, int rs)
{
#pragma unroll
    for (int s = 0; s < 3; ++s) {
        int len   = 64 >> (2 * s);
        int qsh   = 4 - 2 * s;         // q = 1<<qsh : 16,4,1
        int q     = 1 << qsh;
        int tstep = 1 << (2 * s);      // 64/len
        __syncthreads();
        for (int g = threadIdx.x; g < 1024; g += 256) {
            int w = g >> 4;            // which of the 64 FFTs
            int f = g & 15;
            int o = f & (q - 1);
            int base = (f >> qsh) * len;
            int A0 = w * rs + (base + o) * es;
            int A1 = A0 + q * es;
            int A2 = A1 + q * es;
            int A3 = A2 + q * es;
            float a0r = re[A0], a0i = im[A0];
            float a1r = re[A1], a1i = im[A1];
            float a2r = re[A2], a2i = im[A2];
            float a3r = re[A3], a3i = im[A3];
            float t0r = a0r + a2r, t0i = a0i + a2i;
            float t1r = a0r - a2r, t1i = a0i - a2i;
            float t2r = a1r + a3r, t2i = a1i + a3i;
            float dr  = a1r - a3r, di  = a1i - a3i;
            float t3r = di,        t3i = -dr;          // -i*(a1-a3)
            float b0r = t0r + t2r, b0i = t0i + t2i;
            float b1r = t1r + t3r, b1i = t1i + t3i;
            float b2r = t0r - t2r, b2i = t0i - t2i;
            float b3r = t1r - t3r, b3i = t1i - t3i;
            int k1 = o * tstep, k2 = k1 + k1, k3 = k2 + k1;
            float c1 = twr[k1], s1 = twi[k1];
            float c2 = twr[k2], s2 = twi[k2];
            float c3 = twr[k3], s3 = twi[k3];
            re[A0] = b0r;                 im[A0] = b0i;
            re[A1] = b1r * c1 - b1i * s1; im[A1] = b1r * s1 + b1i * c1;
            re[A2] = b2r * c2 - b2i * s2; im[A2] = b2r * s2 + b2i * c2;
            re[A3] = b3r * c3 - b3i * s3; im[A3] = b3r * s3 + b3i * c3;
        }
    }
}

// ---------------- radix-4 DIT inverse (consumes digit-reversed) ----------------
// NOTE: unscaled (×64 per 1D FFT); caller applies 1/4096 after both axes.
__device__ void fft64_inv(float* re, float* im, const float* twr, const float* twi,
                          int es, int rs)
{
#pragma unroll
    for (int s = 0; s < 3; ++s) {
        int len   = 4 << (2 * s);
        int qsh   = 2 * s;             // q = 1,4,16
        int q     = 1 << qsh;
        int tstep = 16 >> (2 * s);
        __syncthreads();
        for (int g = threadIdx.x; g < 1024; g += 256) {
            int w = g >> 4;
            int f = g & 15;
            int o = f & (q - 1);
            int base = (f >> qsh) * len;
            int A0 = w * rs + (base + o) * es;
            int A1 = A0 + q * es;
            int A2 = A1 + q * es;
            int A3 = A2 + q * es;
            int k1 = o * tstep, k2 = k1 + k1, k3 = k2 + k1;
            float c1 = twr[k1], s1 = -twi[k1];   // conj twiddles
            float c2 = twr[k2], s2 = -twi[k2];
            float c3 = twr[k3], s3 = -twi[k3];
            float a0r = re[A0], a0i = im[A0];
            float x1r = re[A1], x1i = im[A1];
            float x2r = re[A2], x2i = im[A2];
            float x3r = re[A3], x3i = im[A3];
            float a1r = x1r * c1 - x1i * s1, a1i = x1r * s1 + x1i * c1;
            float a2r = x2r * c2 - x2i * s2, a2i = x2r * s2 + x2i * c2;
            float a3r = x3r * c3 - x3i * s3, a3i = x3r * s3 + x3i * c3;
            float t0r = a0r + a2r, t0i = a0i + a2i;
            float t1r = a0r - a2r, t1i = a0i - a2i;
            float t2r = a1r + a3r, t2i = a1i + a3i;
            float dr  = a1r - a3r, di  = a1i - a3i;
            float t3r = -di,       t3i = dr;          // +i*(a1-a3)
            re[A0] = t0r + t2r; im[A0] = t0i + t2i;
            re[A1] = t1r + t3r; im[A1] = t1i + t3i;
            re[A2] = t0r - t2r; im[A2] = t0i - t2i;
            re[A3] = t1r - t3r; im[A3] = t1i - t3i;
        }
    }
}

// Per-row: x (4096 reals viewed 64x64) -> real(ifft2(wfft .* fft2(x))),
// optional input scaling by s[I]*s[K], optional diag (var) extraction.
__global__ __launch_bounds__(256)
void row_conv_kernel(const float* in, float* out,
                     const float2* __restrict__ wfft_br,
                     const float* __restrict__ sstd,  // null or [B][NN] std vector
                     float* var_out,                  // null or [B*NN] diag out
                     int rows_per_batch)
{
    __shared__ float re[DXY * PITCH];
    __shared__ float im[DXY * PITCH];
    __shared__ float twr[64], twi[64];

    int tid = threadIdx.x;
    int row = blockIdx.x;
    long long rowoff = (long long)row * NN;
    int b  = row / rows_per_batch;
    int rI = row - b * rows_per_batch;

    if (tid < 64) {
        float ang = -6.28318530717958647692f * (float)tid / 64.0f;
        twr[tid] = cosf(ang);
        twi[tid] = sinf(ang);
    }

    float sI = 1.0f;
    if (sstd) sI = sstd[(long long)b * NN + rI];

#pragma unroll
    for (int i = 0; i < 16; ++i) {
        int p = tid + 256 * i;
        float v = in[rowoff + p];
        if (sstd) v *= sI * sstd[(long long)b * NN + p];
        re[lpos(p)] = v;
        im[lpos(p)] = 0.0f;
    }

    fft64_fwd(re, im, twr, twi, 1, PITCH);   // along fast axis (c)
    fft64_fwd(re, im, twr, twi, PITCH, 1);   // along slow axis (r)
    __syncthreads();

#pragma unroll
    for (int i = 0; i < 16; ++i) {
        int p = tid + 256 * i;
        float2 wv = wfft_br[p];              // same digit-reversed layout
        int a = lpos(p);
        float xr = re[a], xi = im[a];
        re[a] = xr * wv.x - xi * wv.y;
        im[a] = xr * wv.y + xi * wv.x;
    }

    fft64_inv(re, im, twr, twi, PITCH, 1);
    fft64_inv(re, im, twr, twi, 1, PITCH);
    __syncthreads();

    const float scale = 1.0f / 4096.0f;
#pragma unroll
    for (int i = 0; i < 16; ++i) {
        int p = tid + 256 * i;
        out[rowoff + p] = re[lpos(p)] * scale;
    }
    if (var_out && tid == 0) {
        var_out[row] = re[lpos(rI)] * scale; // diag element z[I = row-within-batch]
    }
}

// wfft in digit-reversed layout, via the SAME forward routine (layouts match).
__global__ __launch_bounds__(256)
void wfft_kernel(const float* __restrict__ w, float2* wfft_br)
{
    __shared__ float re[DXY * PITCH];
    __shared__ float im[DXY * PITCH];
    __shared__ float twr[64], twi[64];
    int tid = threadIdx.x;
    if (tid < 64) {
        float ang = -6.28318530717958647692f * (float)tid / 64.0f;
        twr[tid] = cosf(ang);
        twi[tid] = sinf(ang);
    }
#pragma unroll
    for (int i = 0; i < 16; ++i) {
        int p = tid + 256 * i;
        re[lpos(p)] = w[p];
        im[lpos(p)] = 0.0f;
    }
    fft64_fwd(re, im, twr, twi, 1, PITCH);
    fft64_fwd(re, im, twr, twi, PITCH, 1);
    __syncthreads();
#pragma unroll
    for (int i = 0; i < 16; ++i) {
        int p = tid + 256 * i;
        wfft_br[p] = make_float2(re[lpos(p)], im[lpos(p)]);
    }
}

// In-place per-batch transpose of a 4096x4096 matrix, 64x64 tile pairs.
__global__ __launch_bounds__(256)
void transpose_inplace_kernel(float* data)
{
    int bx = blockIdx.x, by = blockIdx.y, b = blockIdx.z;
    if (by > bx) return;
    __shared__ float tA[64][PITCH];
    __shared__ float tB[64][PITCH];
    int tx = threadIdx.x & 63, ty = threadIdx.x >> 6;
    long long base = (long long)b * NN * NN;
    float* A  = data + base + (long long)(by * 64) * NN + bx * 64;
    float* Bt = data + base + (long long)(bx * 64) * NN + by * 64;
    if (bx == by) {
        for (int r = ty; r < 64; r += 4) tA[r][tx] = A[(long long)r * NN + tx];
        __syncthreads();
        for (int r = ty; r < 64; r += 4) A[(long long)r * NN + tx] = tA[tx][r];
    } else {
        for (int r = ty; r < 64; r += 4) {
            tA[r][tx] = A[(long long)r * NN + tx];
            tB[r][tx] = Bt[(long long)r * NN + tx];
        }
        __syncthreads();
        for (int r = ty; r < 64; r += 4) {
            A[(long long)r * NN + tx]  = tB[tx][r];
            Bt[(long long)r * NN + tx] = tA[tx][r];
        }
    }
}

// data holds R[b][K][I] = cov_out[I][K]; write corr_out[b][I][K] =
// R[b][K][I] * rstd[I] * rstd[K]  (in-place transpose + normalize).
__global__ __launch_bounds__(256)
void norm_transpose_inplace_kernel(float* data, const float* __restrict__ rstd)
{
    int bx = blockIdx.x, by = blockIdx.y, b = blockIdx.z;
    if (by > bx) return;
    __shared__ float tA[64][PITCH];
    __shared__ float tB[64][PITCH];
    int tx = threadIdx.x & 63, ty = threadIdx.x >> 6;
    long long base = (long long)b * NN * NN;
    const float* rs = rstd + (long long)b * NN;
    float* A  = data + base + (long long)(by * 64) * NN + bx * 64;
    float* Bt = data + base + (long long)(bx * 64) * NN + by * 64;
    float rcA = rs[bx * 64 + tx];   // col factor for writes into A (col = bx*64+tx)
    float rcB = rs[by * 64 + tx];   // col factor for writes into Bt
    if (bx == by) {
        for (int r = ty; r < 64; r += 4) tA[r][tx] = A[(long long)r * NN + tx];
        __syncthreads();
        for (int r = ty; r < 64; r += 4)
            A[(long long)r * NN + tx] = tA[tx][r] * rs[by * 64 + r] * rcA;
    } else {
        for (int r = ty; r < 64; r += 4) {
            tA[r][tx] = A[(long long)r * NN + tx];
            tB[r][tx] = Bt[(long long)r * NN + tx];
        }
        __syncthreads();
        for (int r = ty; r < 64; r += 4) {
            A[(long long)r * NN + tx]  = tB[tx][r] * rs[by * 64 + r] * rcA;
            Bt[(long long)r * NN + tx] = tA[tx][r] * rs[bx * 64 + r] * rcB;
        }
    }
}

__global__ __launch_bounds__(256)
void std_kernel(const float* __restrict__ var, float* std_out, float* rstd, int n)
{
    int i = blockIdx.x * 256 + threadIdx.x;
    if (i < n) {
        float s = sqrtf(fmaxf(var[i], 1e-12f));
        std_out[i] = s;
        rstd[i] = 1.0f / s;
    }
}

extern "C" void kernel_launch(void* const* d_in, const int* in_sizes, int n_in,
                              void* d_out, int out_size, void* d_ws, size_t ws_size,
                              hipStream_t stream)
{
    const float* mean_in = (const float*)d_in[0];   // [2][64][64]
    const float* std_in  = (const float*)d_in[1];   // [2][64][64]
    const float* corr_in = (const float*)d_in[2];   // [2][4096][4096]
    const float* weight  = (const float*)d_in[3];   // [64][64]

    float* out      = (float*)d_out;
    float* mean_out = out;               // 8192
    float* std_out  = out + 8192;        // 8192
    float* corr_out = out + 16384;       // 2*4096*4096

    float*  ws      = (float*)d_ws;
    float2* wfft_br = (float2*)ws;       // 4096 float2  (8192 floats)
    float*  var_ws  = ws + 8192;         // 8192 floats
    float*  rstd_ws = ws + 16384;        // 8192 floats

    // wfft (digit-reversed layout)
    wfft_kernel<<<1, 256, 0, stream>>>(weight, wfft_br);

    // mean path: 2 rows, no scaling, no diag
    row_conv_kernel<<<NB, 256, 0, stream>>>(mean_in, mean_out, wfft_br,
                                            nullptr, nullptr, 1);

    // K1: conv along K for every row (with s[I]*s[K] scaling) -> corr_out = X1
    row_conv_kernel<<<NB * NN, 256, 0, stream>>>(corr_in, corr_out, wfft_br,
                                                 std_in, nullptr, NN);

    // K2: in-place transpose -> X1^T
    dim3 tg(64, 64, NB);
    transpose_inplace_kernel<<<tg, 256, 0, stream>>>(corr_out);

    // K3: conv along I (rows of X1^T), in place; extract diag -> var
    row_conv_kernel<<<NB * NN, 256, 0, stream>>>(corr_out, corr_out, wfft_br,
                                                 nullptr, var_ws, NN);

    // std_out = sqrt(max(var,1e-12)); rstd = 1/std
    std_kernel<<<(NB * NN + 255) / 256, 256, 0, stream>>>(var_ws, std_out,
                                                          rstd_ws, NB * NN);

    // K4: in-place transpose + normalize -> corr_out
    norm_transpose_inplace_kernel<<<tg, 256, 0, stream>>>(corr_out, rstd_ws);
}

// Round 2
// 509.683 us; speedup vs baseline: 1.5817x; 1.5817x over previous
//
#include <hip/hip_runtime.h>
#include <math.h>

#define DXY   64
#define NN    4096      // 64*64
#define NB    2
#define PITCH 65        // LDS row pitch (bank-conflict pad)

__device__ __forceinline__ int lpos(int p) {
    return (p >> 6) * PITCH + (p & 63);
}

// ---------------- radix-4 DIF forward (output digit-reversed) ----------------
// es = element stride along transform axis, rs = stride between the 64 FFTs.
// Work mapping: w = g&63 (lane id -> conflict-free LDS), f = g>>6 (wave-uniform
// -> twiddle reads are broadcasts).
__device__ void fft64_fwd(float* re, float* im, const float* twr, const float* twi,
                          int es, int rs)
{
#pragma unroll
    for (int s = 0; s < 3; ++s) {
        int len   = 64 >> (2 * s);
        int qsh   = 4 - 2 * s;         // q = 1<<qsh : 16,4,1
        int q     = 1 << qsh;
        int tstep = 1 << (2 * s);      // 64/len
        __syncthreads();
#pragma unroll
        for (int g = threadIdx.x; g < 1024; g += 256) {
            int w = g & 63;            // which of the 64 FFTs (lane-distinct)
            int f = g >> 6;            // butterfly index (wave-uniform)
            int o = f & (q - 1);
            int base = (f >> qsh) * len;
            int A0 = w * rs + (base + o) * es;
            int A1 = A0 + q * es;
            int A2 = A1 + q * es;
            int A3 = A2 + q * es;
            float a0r = re[A0], a0i = im[A0];
            float a1r = re[A1], a1i = im[A1];
            float a2r = re[A2], a2i = im[A2];
            float a3r = re[A3], a3i = im[A3];
            float t0r = a0r + a2r, t0i = a0i + a2i;
            float t1r = a0r - a2r, t1i = a0i - a2i;
            float t2r = a1r + a3r, t2i = a1i + a3i;
            float dr  = a1r - a3r, di  = a1i - a3i;
            float t3r = di,        t3i = -dr;          // -i*(a1-a3)
            float b0r = t0r + t2r, b0i = t0i + t2i;
            float b1r = t1r + t3r, b1i = t1i + t3i;
            float b2r = t0r - t2r, b2i = t0i - t2i;
            float b3r = t1r - t3r, b3i = t1i - t3i;
            int k1 = o * tstep, k2 = k1 + k1, k3 = k2 + k1;
            float c1 = twr[k1], s1 = twi[k1];
            float c2 = twr[k2], s2 = twi[k2];
            float c3 = twr[k3], s3 = twi[k3];
            re[A0] = b0r;                 im[A0] = b0i;
            re[A1] = b1r * c1 - b1i * s1; im[A1] = b1r * s1 + b1i * c1;
            re[A2] = b2r * c2 - b2i * s2; im[A2] = b2r * s2 + b2i * c2;
            re[A3] = b3r * c3 - b3i * s3; im[A3] = b3r * s3 + b3i * c3;
        }
    }
}

// ---------------- radix-4 DIT inverse (consumes digit-reversed) ----------------
// NOTE: unscaled (×64 per 1D FFT); caller applies 1/4096 after both axes.
__device__ void fft64_inv(float* re, float* im, const float* twr, const float* twi,
                          int es, int rs)
{
#pragma unroll
    for (int s = 0; s < 3; ++s) {
        int len   = 4 << (2 * s);
        int qsh   = 2 * s;             // q = 1,4,16
        int q     = 1 << qsh;
        int tstep = 16 >> (2 * s);
        __syncthreads();
#pragma unroll
        for (int g = threadIdx.x; g < 1024; g += 256) {
            int w = g & 63;
            int f = g >> 6;
            int o = f & (q - 1);
            int base = (f >> qsh) * len;
            int A0 = w * rs + (base + o) * es;
            int A1 = A0 + q * es;
            int A2 = A1 + q * es;
            int A3 = A2 + q * es;
            int k1 = o * tstep, k2 = k1 + k1, k3 = k2 + k1;
            float c1 = twr[k1], s1 = -twi[k1];   // conj twiddles
            float c2 = twr[k2], s2 = -twi[k2];
            float c3 = twr[k3], s3 = -twi[k3];
            float a0r = re[A0], a0i = im[A0];
            float x1r = re[A1], x1i = im[A1];
            float x2r = re[A2], x2i = im[A2];
            float x3r = re[A3], x3i = im[A3];
            float a1r = x1r * c1 - x1i * s1, a1i = x1r * s1 + x1i * c1;
            float a2r = x2r * c2 - x2i * s2, a2i = x2r * s2 + x2i * c2;
            float a3r = x3r * c3 - x3i * s3, a3i = x3r * s3 + x3i * c3;
            float t0r = a0r + a2r, t0i = a0i + a2i;
            float t1r = a0r - a2r, t1i = a0i - a2i;
            float t2r = a1r + a3r, t2i = a1i + a3i;
            float dr  = a1r - a3r, di  = a1i - a3i;
            float t3r = -di,       t3i = dr;          // +i*(a1-a3)
            re[A0] = t0r + t2r; im[A0] = t0i + t2i;
            re[A1] = t1r + t3r; im[A1] = t1i + t3i;
            re[A2] = t0r - t2r; im[A2] = t0i - t2i;
            re[A3] = t1r - t3r; im[A3] = t1i - t3i;
        }
    }
}

// Packed per-row-pair conv: rows (2*blk, 2*blk+1) become re/im of ONE complex
// 64x64 2D FFT conv (w is real => conv(a)+i*conv(b) = ifft(W.*fft(a+ib))).
// Optional input scaling by s[I]*s[K], optional diag (var) extraction.
__global__ __launch_bounds__(256)
void row_conv2_kernel(const float* __restrict__ in, float* __restrict__ out,
                      const float2* __restrict__ wfft_br,
                      const float* __restrict__ sstd,  // null or [B][NN] std vector
                      float* var_out)                  // null or [B*NN] diag out
{
    __shared__ float re[DXY * PITCH];
    __shared__ float im[DXY * PITCH];
    __shared__ float twr[64], twi[64];

    int tid  = threadIdx.x;
    int row0 = 2 * blockIdx.x;            // global row index (across batches)
    long long off0 = (long long)row0 * NN;
    long long off1 = off0 + NN;
    int b   = row0 >> 12;                 // row0 / NN
    int rI0 = row0 & (NN - 1);
    int rI1 = rI0 + 1;

    if (tid < 64) {
        float ang = -6.28318530717958647692f * (float)tid / 64.0f;
        twr[tid] = cosf(ang);
        twi[tid] = sinf(ang);
    }

    float sI0 = 1.0f, sI1 = 1.0f;
    const float* sb = nullptr;
    if (sstd) {
        sb  = sstd + (long long)b * NN;
        sI0 = sb[rI0];
        sI1 = sb[rI1];
    }

#pragma unroll
    for (int i = 0; i < 4; ++i) {
        int p = (tid + 256 * i) * 4;
        float4 a = *(const float4*)(in + off0 + p);
        float4 c = *(const float4*)(in + off1 + p);
        if (sb) {
            float4 s4 = *(const float4*)(sb + p);
            a.x *= sI0 * s4.x; a.y *= sI0 * s4.y; a.z *= sI0 * s4.z; a.w *= sI0 * s4.w;
            c.x *= sI1 * s4.x; c.y *= sI1 * s4.y; c.z *= sI1 * s4.z; c.w *= sI1 * s4.w;
        }
        int q0 = lpos(p);
        re[q0] = a.x; re[q0+1] = a.y; re[q0+2] = a.z; re[q0+3] = a.w;
        im[q0] = c.x; im[q0+1] = c.y; im[q0+2] = c.z; im[q0+3] = c.w;
    }

    fft64_fwd(re, im, twr, twi, 1, PITCH);   // along fast axis
    fft64_fwd(re, im, twr, twi, PITCH, 1);   // along slow axis
    __syncthreads();

#pragma unroll
    for (int i = 0; i < 16; ++i) {
        int p = tid + 256 * i;
        float2 wv = wfft_br[p];              // same digit-reversed layout
        int a = lpos(p);
        float xr = re[a], xi = im[a];
        re[a] = xr * wv.x - xi * wv.y;
        im[a] = xr * wv.y + xi * wv.x;
    }

    fft64_inv(re, im, twr, twi, PITCH, 1);
    fft64_inv(re, im, twr, twi, 1, PITCH);
    __syncthreads();

    const float scale = 1.0f / 4096.0f;
#pragma unroll
    for (int i = 0; i < 4; ++i) {
        int p = (tid + 256 * i) * 4;
        int q0 = lpos(p);
        float4 a, c;
        a.x = re[q0] * scale; a.y = re[q0+1] * scale;
        a.z = re[q0+2] * scale; a.w = re[q0+3] * scale;
        c.x = im[q0] * scale; c.y = im[q0+1] * scale;
        c.z = im[q0+2] * scale; c.w = im[q0+3] * scale;
        *(float4*)(out + off0 + p) = a;
        *(float4*)(out + off1 + p) = c;
    }
    if (var_out && tid == 0) {
        var_out[row0]     = re[lpos(rI0)] * scale;
        var_out[row0 + 1] = im[lpos(rI1)] * scale;
    }
}

// wfft in digit-reversed layout, via the SAME forward routine (layouts match).
__global__ __launch_bounds__(256)
void wfft_kernel(const float* __restrict__ w, float2* wfft_br)
{
    __shared__ float re[DXY * PITCH];
    __shared__ float im[DXY * PITCH];
    __shared__ float twr[64], twi[64];
    int tid = threadIdx.x;
    if (tid < 64) {
        float ang = -6.28318530717958647692f * (float)tid / 64.0f;
        twr[tid] = cosf(ang);
        twi[tid] = sinf(ang);
    }
#pragma unroll
    for (int i = 0; i < 16; ++i) {
        int p = tid + 256 * i;
        re[lpos(p)] = w[p];
        im[lpos(p)] = 0.0f;
    }
    fft64_fwd(re, im, twr, twi, 1, PITCH);
    fft64_fwd(re, im, twr, twi, PITCH, 1);
    __syncthreads();
#pragma unroll
    for (int i = 0; i < 16; ++i) {
        int p = tid + 256 * i;
        wfft_br[p] = make_float2(re[lpos(p)], im[lpos(p)]);
    }
}

// In-place per-batch transpose of a 4096x4096 matrix, 64x64 tile pairs.
__global__ __launch_bounds__(256)
void transpose_inplace_kernel(float* data)
{
    int bx = blockIdx.x, by = blockIdx.y, b = blockIdx.z;
    if (by > bx) return;
    __shared__ float tA[64][PITCH];
    __shared__ float tB[64][PITCH];
    int tx = threadIdx.x & 63, ty = threadIdx.x >> 6;
    long long base = (long long)b * NN * NN;
    float* A  = data + base + (long long)(by * 64) * NN + bx * 64;
    float* Bt = data + base + (long long)(bx * 64) * NN + by * 64;
    if (bx == by) {
        for (int r = ty; r < 64; r += 4) tA[r][tx] = A[(long long)r * NN + tx];
        __syncthreads();
        for (int r = ty; r < 64; r += 4) A[(long long)r * NN + tx] = tA[tx][r];
    } else {
        for (int r = ty; r < 64; r += 4) {
            tA[r][tx] = A[(long long)r * NN + tx];
            tB[r][tx] = Bt[(long long)r * NN + tx];
        }
        __syncthreads();
        for (int r = ty; r < 64; r += 4) {
            A[(long long)r * NN + tx]  = tB[tx][r];
            Bt[(long long)r * NN + tx] = tA[tx][r];
        }
    }
}

// data holds R[b][K][I] = cov_out[I][K]; write corr_out[b][I][K] =
// R[b][K][I] * rstd[I] * rstd[K]  (in-place transpose + normalize).
__global__ __launch_bounds__(256)
void norm_transpose_inplace_kernel(float* data, const float* __restrict__ rstd)
{
    int bx = blockIdx.x, by = blockIdx.y, b = blockIdx.z;
    if (by > bx) return;
    __shared__ float tA[64][PITCH];
    __shared__ float tB[64][PITCH];
    int tx = threadIdx.x & 63, ty = threadIdx.x >> 6;
    long long base = (long long)b * NN * NN;
    const float* rs = rstd + (long long)b * NN;
    float* A  = data + base + (long long)(by * 64) * NN + bx * 64;
    float* Bt = data + base + (long long)(bx * 64) * NN + by * 64;
    float rcA = rs[bx * 64 + tx];   // col factor for writes into A (col = bx*64+tx)
    float rcB = rs[by * 64 + tx];   // col factor for writes into Bt
    if (bx == by) {
        for (int r = ty; r < 64; r += 4) tA[r][tx] = A[(long long)r * NN + tx];
        __syncthreads();
        for (int r = ty; r < 64; r += 4)
            A[(long long)r * NN + tx] = tA[tx][r] * rs[by * 64 + r] * rcA;
    } else {
        for (int r = ty; r < 64; r += 4) {
            tA[r][tx] = A[(long long)r * NN + tx];
            tB[r][tx] = Bt[(long long)r * NN + tx];
        }
        __syncthreads();
        for (int r = ty; r < 64; r += 4) {
            A[(long long)r * NN + tx]  = tB[tx][r] * rs[by * 64 + r] * rcA;
            Bt[(long long)r * NN + tx] = tA[tx][r] * rs[bx * 64 + r] * rcB;
        }
    }
}

__global__ __launch_bounds__(256)
void std_kernel(const float* __restrict__ var, float* std_out, float* rstd, int n)
{
    int i = blockIdx.x * 256 + threadIdx.x;
    if (i < n) {
        float s = sqrtf(fmaxf(var[i], 1e-12f));
        std_out[i] = s;
        rstd[i] = 1.0f / s;
    }
}

extern "C" void kernel_launch(void* const* d_in, const int* in_sizes, int n_in,
                              void* d_out, int out_size, void* d_ws, size_t ws_size,
                              hipStream_t stream)
{
    const float* mean_in = (const float*)d_in[0];   // [2][64][64]
    const float* std_in  = (const float*)d_in[1];   // [2][64][64]
    const float* corr_in = (const float*)d_in[2];   // [2][4096][4096]
    const float* weight  = (const float*)d_in[3];   // [64][64]

    float* out      = (float*)d_out;
    float* mean_out = out;               // 8192
    float* std_out  = out + 8192;        // 8192
    float* corr_out = out + 16384;       // 2*4096*4096

    float*  ws      = (float*)d_ws;
    float2* wfft_br = (float2*)ws;       // 4096 float2  (8192 floats)
    float*  var_ws  = ws + 8192;         // 8192 floats
    float*  rstd_ws = ws + 16384;        // 8192 floats

    // wfft (digit-reversed layout)
    wfft_kernel<<<1, 256, 0, stream>>>(weight, wfft_br);

    // mean path: batch0 row -> re, batch1 row -> im of one packed block
    row_conv2_kernel<<<1, 256, 0, stream>>>(mean_in, mean_out, wfft_br,
                                            nullptr, nullptr);

    // K1: conv along K for every row pair (with s[I]*s[K] scaling) -> X1
    row_conv2_kernel<<<NB * NN / 2, 256, 0, stream>>>(corr_in, corr_out, wfft_br,
                                                      std_in, nullptr);

    // K2: in-place transpose -> X1^T
    dim3 tg(64, 64, NB);
    transpose_inplace_kernel<<<tg, 256, 0, stream>>>(corr_out);

    // K3: conv along I (row pairs of X1^T), in place; extract diag -> var
    row_conv2_kernel<<<NB * NN / 2, 256, 0, stream>>>(corr_out, corr_out, wfft_br,
                                                      nullptr, var_ws);

    // std_out = sqrt(max(var,1e-12)); rstd = 1/std
    std_kernel<<<(NB * NN + 255) / 256, 256, 0, stream>>>(var_ws, std_out,
                                                          rstd_ws, NB * NN);

    // K4: in-place transpose + normalize -> corr_out
    norm_transpose_inplace_kernel<<<tg, 256, 0, stream>>>(corr_out, rstd_ws);
}

// Round 3
// 482.216 us; speedup vs baseline: 1.6718x; 1.0570x over previous
//
#include <hip/hip_runtime.h>
#include <math.h>

#define DXY   64
#define NN    4096      // 64*64
#define NB    2
#define CP    65        // LDS complex pitch (bank-spread pad)

#define C16 0.9238795325112867f
#define S16 0.3826834323650898f
#define R22 0.7071067811865476f

__device__ __forceinline__ void cmul_ip(float2& a, float wr, float wi) {
    float t = a.x * wr - a.y * wi;
    a.y = a.x * wi + a.y * wr;
    a.x = t;
}

// radix-4 core in place on y[i0..i3]; inv selects +i rotation (conj core, unscaled)
__device__ __forceinline__ void bf4(float2* y, int i0, int i1, int i2, int i3, int inv) {
    float2 a0 = y[i0], a1 = y[i1], a2 = y[i2], a3 = y[i3];
    float t0r = a0.x + a2.x, t0i = a0.y + a2.y;
    float t1r = a0.x - a2.x, t1i = a0.y - a2.y;
    float t2r = a1.x + a3.x, t2i = a1.y + a3.y;
    float dr  = a1.x - a3.x, di  = a1.y - a3.y;
    float t3r, t3i;
    if (inv) { t3r = -di; t3i = dr; } else { t3r = di; t3i = -dr; }
    y[i0] = make_float2(t0r + t2r, t0i + t2i);
    y[i1] = make_float2(t1r + t3r, t1i + t3i);
    y[i2] = make_float2(t0r - t2r, t0i - t2i);
    y[i3] = make_float2(t1r - t3r, t1i - t3i);
}

// 16-pt DIF radix-4 (natural in, base-4 digit-reversed out), constant twiddles
__device__ __forceinline__ void fft16_fwd(float2* y) {
    bf4(y, 0, 4, 8, 12, 0);
    bf4(y, 1, 5, 9, 13, 0);
    cmul_ip(y[5],  C16, -S16); cmul_ip(y[9],  R22, -R22); cmul_ip(y[13],  S16, -C16);
    bf4(y, 2, 6, 10, 14, 0);
    cmul_ip(y[6],  R22, -R22); cmul_ip(y[10], 0.f, -1.f); cmul_ip(y[14], -R22, -R22);
    bf4(y, 3, 7, 11, 15, 0);
    cmul_ip(y[7],  S16, -C16); cmul_ip(y[11], -R22, -R22); cmul_ip(y[15], -C16,  S16);
    bf4(y, 0, 1, 2, 3, 0); bf4(y, 4, 5, 6, 7, 0);
    bf4(y, 8, 9, 10, 11, 0); bf4(y, 12, 13, 14, 15, 0);
}

// exact unscaled inverse of fft16_fwd (consumes its layout), = 16 * IDFT16
__device__ __forceinline__ void fft16_inv(float2* y) {
    bf4(y, 0, 1, 2, 3, 1); bf4(y, 4, 5, 6, 7, 1);
    bf4(y, 8, 9, 10, 11, 1); bf4(y, 12, 13, 14, 15, 1);
    cmul_ip(y[5],  C16,  S16); cmul_ip(y[9],  R22,  R22); cmul_ip(y[13],  S16,  C16);
    cmul_ip(y[6],  R22,  R22); cmul_ip(y[10], 0.f,  1.f); cmul_ip(y[14], -R22,  R22);
    cmul_ip(y[7],  S16,  C16); cmul_ip(y[11], -R22,  R22); cmul_ip(y[15], -C16, -S16);
    bf4(y, 0, 4, 8, 12, 1); bf4(y, 1, 5, 9, 13, 1);
    bf4(y, 2, 6, 10, 14, 1); bf4(y, 3, 7, 11, 15, 1);
}

// Forward 64-pt FFT over 64 lines. Thread (u,k1): cross radix-4 gather (4-way
// broadcast reads) -> in-register 16-pt FFT -> [optional W-mult] -> write own
// segment [16k1..16k1+15]. US = line stride, NS = element stride (complex).
template<int US, int NS, bool FUSEW>
__device__ void fwd_pass(float2* z, const float2* __restrict__ wf, int u, int k1,
                         float c1r, float c1i, float s2, float2 Wb)
{
    const int B = u * US;
    float2 y[16];
    float twr = 1.f, twi = 0.f;
#pragma unroll
    for (int n2 = 0; n2 < 16; ++n2) {
        float2 x0 = z[B + n2 * NS];
        float2 x1 = z[B + (n2 + 16) * NS];
        float2 x2 = z[B + (n2 + 32) * NS];
        float2 x3 = z[B + (n2 + 48) * NS];
        float er  = fmaf(s2, x2.x, x0.x), ei = fmaf(s2, x2.y, x0.y);
        float orr = fmaf(s2, x3.x, x1.x), oi = fmaf(s2, x3.y, x1.y);
        float br = er + c1r * orr - c1i * oi;
        float bi = ei + c1r * oi + c1i * orr;
        y[n2].x = twr * br - twi * bi;
        y[n2].y = twr * bi + twi * br;
        float t = twr * Wb.x - twi * Wb.y;
        twi = twr * Wb.y + twi * Wb.x;
        twr = t;
    }
    fft16_fwd(y);
    if (FUSEW) {
#pragma unroll
        for (int p = 0; p < 16; ++p) {
            float2 wv = wf[(16 * k1 + p) * 64 + u];
            cmul_ip(y[p], wv.x, wv.y);
        }
    }
    __syncthreads();   // all gather reads complete before anyone overwrites
#pragma unroll
    for (int p = 0; p < 16; ++p) z[B + (16 * k1 + p) * NS] = y[p];
    __syncthreads();
}

// Inverse: read own segment -> in-register 16-pt IFFT -> conj cross twiddle ->
// store H -> gather across segments -> conj cross radix-4 -> write natural.
template<int US, int NS>
__device__ void inv_pass(float2* z, int u, int k1,
                         float ci1r, float ci1i, float s2, float2 Wbc)
{
    const int B = u * US;
    float2 y[16];
#pragma unroll
    for (int p = 0; p < 16; ++p) y[p] = z[B + (16 * k1 + p) * NS];
    fft16_inv(y);
    float twr = 1.f, twi = 0.f;
#pragma unroll
    for (int n2 = 0; n2 < 16; ++n2) {
        cmul_ip(y[n2], twr, twi);
        float t = twr * Wbc.x - twi * Wbc.y;
        twi = twr * Wbc.y + twi * Wbc.x;
        twr = t;
    }
#pragma unroll
    for (int n2 = 0; n2 < 16; ++n2) z[B + (16 * k1 + n2) * NS] = y[n2]; // own slots
    __syncthreads();
    float2 xx[16];
#pragma unroll
    for (int n2 = 0; n2 < 16; ++n2) {
        float2 h0 = z[B + n2 * NS];
        float2 h1 = z[B + (n2 + 16) * NS];
        float2 h2 = z[B + (n2 + 32) * NS];
        float2 h3 = z[B + (n2 + 48) * NS];
        float er  = fmaf(s2, h2.x, h0.x), ei = fmaf(s2, h2.y, h0.y);
        float orr = fmaf(s2, h3.x, h1.x), oi = fmaf(s2, h3.y, h1.y);
        xx[n2].x = er + ci1r * orr - ci1i * oi;
        xx[n2].y = ei + ci1r * oi + ci1i * orr;
    }
    __syncthreads();
#pragma unroll
    for (int n2 = 0; n2 < 16; ++n2) z[B + (16 * k1 + n2) * NS] = xx[n2];
    __syncthreads();
}

// Packed per-row-pair conv: rows (2blk, 2blk+1) -> re/im of one complex 64x64
// 2D FFT conv. Optional s[I]*s[K] input scaling, optional diag extraction.
__global__ __launch_bounds__(256, 4)
void row_conv2_kernel(const float* __restrict__ in, float* __restrict__ out,
                      const float2* __restrict__ wfft_br,
                      const float* __restrict__ sstd, float* var_out)
{
    __shared__ float2 z[64 * CP];
    const int tid = threadIdx.x;
    const int u   = ((tid >> 6) << 4) | (tid & 15);
    const int k1  = (tid >> 4) & 3;
    const float c1r = (k1 == 0) ? 1.f : ((k1 == 2) ? -1.f : 0.f);
    const float c1i = (k1 == 1) ? -1.f : ((k1 == 3) ? 1.f : 0.f);
    const float s2  = (k1 & 1) ? -1.f : 1.f;
    const float ang = -0.09817477042468103f * (float)k1;   // -2π/64 * k1
    const float2 Wb  = make_float2(cosf(ang), sinf(ang));
    const float2 Wbc = make_float2(Wb.x, -Wb.y);
    const float ci1r = c1r, ci1i = -c1i;

    const int row0 = 2 * blockIdx.x;
    const long long off0 = (long long)row0 * NN, off1 = off0 + NN;
    const int b   = row0 >> 12;
    const int rI0 = row0 & (NN - 1), rI1 = rI0 + 1;
    const float* sb = nullptr;
    float sI0 = 1.f, sI1 = 1.f;
    if (sstd) { sb = sstd + (long long)b * NN; sI0 = sb[rI0]; sI1 = sb[rI1]; }

#pragma unroll
    for (int i = 0; i < 4; ++i) {
        int idx = tid + 256 * i;
        int p = idx * 4;
        int r = p >> 6, c = p & 63;
        float4 a  = *(const float4*)(in + off0 + p);
        float4 cc = *(const float4*)(in + off1 + p);
        if (sb) {
            float4 s4 = *(const float4*)(sb + p);
            a.x *= sI0 * s4.x; a.y *= sI0 * s4.y; a.z *= sI0 * s4.z; a.w *= sI0 * s4.w;
            cc.x *= sI1 * s4.x; cc.y *= sI1 * s4.y; cc.z *= sI1 * s4.z; cc.w *= sI1 * s4.w;
        }
        float2* zp = z + r * CP + c;
        zp[0] = make_float2(a.x, cc.x);
        zp[1] = make_float2(a.y, cc.y);
        zp[2] = make_float2(a.z, cc.z);
        zp[3] = make_float2(a.w, cc.w);
    }
    __syncthreads();

    fwd_pass<CP, 1, false>(z, nullptr,  u, k1, c1r, c1i, s2, Wb);  // fast axis
    fwd_pass<1, CP, true >(z, wfft_br,  u, k1, c1r, c1i, s2, Wb);  // slow axis + W
    inv_pass<1, CP>(z, u, k1, ci1r, ci1i, s2, Wbc);                // slow axis
    inv_pass<CP, 1>(z, u, k1, ci1r, ci1i, s2, Wbc);                // fast axis

    const float scale = 1.0f / 4096.0f;
#pragma unroll
    for (int i = 0; i < 4; ++i) {
        int idx = tid + 256 * i;
        int p = idx * 4;
        int r = p >> 6, c = p & 63;
        const float2* zp = z + r * CP + c;
        float4 a, cc;
        a.x = zp[0].x * scale; a.y = zp[1].x * scale;
        a.z = zp[2].x * scale; a.w = zp[3].x * scale;
        cc.x = zp[0].y * scale; cc.y = zp[1].y * scale;
        cc.z = zp[2].y * scale; cc.w = zp[3].y * scale;
        *(float4*)(out + off0 + p) = a;
        *(float4*)(out + off1 + p) = cc;
    }
    if (var_out && tid == 0) {
        var_out[row0]     = z[(rI0 >> 6) * CP + (rI0 & 63)].x * scale;
        var_out[row0 + 1] = z[(rI1 >> 6) * CP + (rI1 & 63)].y * scale;
    }
}

// wfft in the transform layout, via the SAME forward passes (layouts match).
__global__ __launch_bounds__(256, 4)
void wfft_kernel(const float* __restrict__ w, float2* wfft_br)
{
    __shared__ float2 z[64 * CP];
    const int tid = threadIdx.x;
    const int u   = ((tid >> 6) << 4) | (tid & 15);
    const int k1  = (tid >> 4) & 3;
    const float c1r = (k1 == 0) ? 1.f : ((k1 == 2) ? -1.f : 0.f);
    const float c1i = (k1 == 1) ? -1.f : ((k1 == 3) ? 1.f : 0.f);
    const float s2  = (k1 & 1) ? -1.f : 1.f;
    const float ang = -0.09817477042468103f * (float)k1;
    const float2 Wb = make_float2(cosf(ang), sinf(ang));

#pragma unroll
    for (int i = 0; i < 16; ++i) {
        int p = tid + 256 * i;
        z[(p >> 6) * CP + (p & 63)] = make_float2(w[p], 0.f);
    }
    __syncthreads();
    fwd_pass<CP, 1, false>(z, nullptr, u, k1, c1r, c1i, s2, Wb);
    fwd_pass<1, CP, false>(z, nullptr, u, k1, c1r, c1i, s2, Wb);
#pragma unroll
    for (int i = 0; i < 16; ++i) {
        int p = tid + 256 * i;
        wfft_br[p] = z[(p >> 6) * CP + (p & 63)];
    }
}

// In-place per-batch transpose, 64x64 tile pairs, float4 global I/O.
__global__ __launch_bounds__(256)
void transpose_inplace_kernel(float* data)
{
    int bx = blockIdx.x, by = blockIdx.y, b = blockIdx.z;
    if (by > bx) return;
    __shared__ float tA[64 * 65];
    __shared__ float tB[64 * 65];
    const int f  = threadIdx.x & 15;
    const int r0 = threadIdx.x >> 4;
    long long base = (long long)b * NN * NN;
    float* A  = data + base + (long long)(by * 64) * NN + bx * 64;
    float* Bt = data + base + (long long)(bx * 64) * NN + by * 64;
    if (bx == by) {
#pragma unroll
        for (int it = 0; it < 4; ++it) {
            int r = r0 + 16 * it;
            float4 v = *(const float4*)(A + (long long)r * NN + 4 * f);
            tA[(4 * f + 0) * 65 + r] = v.x; tA[(4 * f + 1) * 65 + r] = v.y;
            tA[(4 * f + 2) * 65 + r] = v.z; tA[(4 * f + 3) * 65 + r] = v.w;
        }
        __syncthreads();
#pragma unroll
        for (int it = 0; it < 4; ++it) {
            int c = r0 + 16 * it;
            float4 v;
            v.x = tA[c * 65 + 4 * f + 0]; v.y = tA[c * 65 + 4 * f + 1];
            v.z = tA[c * 65 + 4 * f + 2]; v.w = tA[c * 65 + 4 * f + 3];
            *(float4*)(A + (long long)c * NN + 4 * f) = v;
        }
    } else {
#pragma unroll
        for (int it = 0; it < 4; ++it) {
            int r = r0 + 16 * it;
            float4 v = *(const float4*)(A + (long long)r * NN + 4 * f);
            float4 w = *(const float4*)(Bt + (long long)r * NN + 4 * f);
            tA[(4 * f + 0) * 65 + r] = v.x; tA[(4 * f + 1) * 65 + r] = v.y;
            tA[(4 * f + 2) * 65 + r] = v.z; tA[(4 * f + 3) * 65 + r] = v.w;
            tB[(4 * f + 0) * 65 + r] = w.x; tB[(4 * f + 1) * 65 + r] = w.y;
            tB[(4 * f + 2) * 65 + r] = w.z; tB[(4 * f + 3) * 65 + r] = w.w;
        }
        __syncthreads();
#pragma unroll
        for (int it = 0; it < 4; ++it) {
            int c = r0 + 16 * it;
            float4 v, w;
            v.x = tB[c * 65 + 4 * f + 0]; v.y = tB[c * 65 + 4 * f + 1];
            v.z = tB[c * 65 + 4 * f + 2]; v.w = tB[c * 65 + 4 * f + 3];
            w.x = tA[c * 65 + 4 * f + 0]; w.y = tA[c * 65 + 4 * f + 1];
            w.z = tA[c * 65 + 4 * f + 2]; w.w = tA[c * 65 + 4 * f + 3];
            *(float4*)(A + (long long)c * NN + 4 * f)  = v;
            *(float4*)(Bt + (long long)c * NN + 4 * f) = w;
        }
    }
}

// data holds R[b][K][I] = cov_out[I][K]; write corr[b][I][K] =
// R[K][I] * rstd[I] * rstd[K]  (in-place transpose + normalize), float4 I/O.
__global__ __launch_bounds__(256)
void norm_transpose_inplace_kernel(float* data, const float* __restrict__ rstd)
{
    int bx = blockIdx.x, by = blockIdx.y, b = blockIdx.z;
    if (by > bx) return;
    __shared__ float tA[64 * 65];
    __shared__ float tB[64 * 65];
    const int f  = threadIdx.x & 15;
    const int r0 = threadIdx.x >> 4;
    long long base = (long long)b * NN * NN;
    const float* rs = rstd + (long long)b * NN;
    float* A  = data + base + (long long)(by * 64) * NN + bx * 64;
    float* Bt = data + base + (long long)(bx * 64) * NN + by * 64;
    float4 rsx_bx = *(const float4*)(rs + bx * 64 + 4 * f);
    float4 rsx_by = *(const float4*)(rs + by * 64 + 4 * f);
    if (bx == by) {
#pragma unroll
        for (int it = 0; it < 4; ++it) {
            int r = r0 + 16 * it;
            float4 v = *(const float4*)(A + (long long)r * NN + 4 * f);
            tA[(4 * f + 0) * 65 + r] = v.x; tA[(4 * f + 1) * 65 + r] = v.y;
            tA[(4 * f + 2) * 65 + r] = v.z; tA[(4 * f + 3) * 65 + r] = v.w;
        }
        __syncthreads();
#pragma unroll
        for (int it = 0; it < 4; ++it) {
            int c = r0 + 16 * it;
            float rr = rs[by * 64 + c];
            float4 v;
            v.x = tA[c * 65 + 4 * f + 0] * rr * rsx_bx.x;
            v.y = tA[c * 65 + 4 * f + 1] * rr * rsx_bx.y;
            v.z = tA[c * 65 + 4 * f + 2] * rr * rsx_bx.z;
            v.w = tA[c * 65 + 4 * f + 3] * rr * rsx_bx.w;
            *(float4*)(A + (long long)c * NN + 4 * f) = v;
        }
    } else {
#pragma unroll
        for (int it = 0; it < 4; ++it) {
            int r = r0 + 16 * it;
            float4 v = *(const float4*)(A + (long long)r * NN + 4 * f);
            float4 w = *(const float4*)(Bt + (long long)r * NN + 4 * f);
            tA[(4 * f + 0) * 65 + r] = v.x; tA[(4 * f + 1) * 65 + r] = v.y;
            tA[(4 * f + 2) * 65 + r] = v.z; tA[(4 * f + 3) * 65 + r] = v.w;
            tB[(4 * f + 0) * 65 + r] = w.x; tB[(4 * f + 1) * 65 + r] = w.y;
            tB[(4 * f + 2) * 65 + r] = w.z; tB[(4 * f + 3) * 65 + r] = w.w;
        }
        __syncthreads();
#pragma unroll
        for (int it = 0; it < 4; ++it) {
            int c = r0 + 16 * it;
            float rA = rs[by * 64 + c];   // row factor for A writes (row by*64+c)
            float rB = rs[bx * 64 + c];   // row factor for Bt writes
            float4 v, w;
            v.x = tB[c * 65 + 4 * f + 0] * rA * rsx_bx.x;
            v.y = tB[c * 65 + 4 * f + 1] * rA * rsx_bx.y;
            v.z = tB[c * 65 + 4 * f + 2] * rA * rsx_bx.z;
            v.w = tB[c * 65 + 4 * f + 3] * rA * rsx_bx.w;
            w.x = tA[c * 65 + 4 * f + 0] * rB * rsx_by.x;
            w.y = tA[c * 65 + 4 * f + 1] * rB * rsx_by.y;
            w.z = tA[c * 65 + 4 * f + 2] * rB * rsx_by.z;
            w.w = tA[c * 65 + 4 * f + 3] * rB * rsx_by.w;
            *(float4*)(A + (long long)c * NN + 4 * f)  = v;
            *(float4*)(Bt + (long long)c * NN + 4 * f) = w;
        }
    }
}

__global__ __launch_bounds__(256)
void std_kernel(const float* __restrict__ var, float* std_out, float* rstd, int n)
{
    int i = blockIdx.x * 256 + threadIdx.x;
    if (i < n) {
        float s = sqrtf(fmaxf(var[i], 1e-12f));
        std_out[i] = s;
        rstd[i] = 1.0f / s;
    }
}

extern "C" void kernel_launch(void* const* d_in, const int* in_sizes, int n_in,
                              void* d_out, int out_size, void* d_ws, size_t ws_size,
                              hipStream_t stream)
{
    const float* mean_in = (const float*)d_in[0];   // [2][64][64]
    const float* std_in  = (const float*)d_in[1];   // [2][64][64]
    const float* corr_in = (const float*)d_in[2];   // [2][4096][4096]
    const float* weight  = (const float*)d_in[3];   // [64][64]

    float* out      = (float*)d_out;
    float* mean_out = out;               // 8192
    float* std_out  = out + 8192;        // 8192
    float* corr_out = out + 16384;       // 2*4096*4096

    float*  ws      = (float*)d_ws;
    float2* wfft_br = (float2*)ws;       // 4096 float2 (8192 floats)
    float*  var_ws  = ws + 8192;         // 8192 floats
    float*  rstd_ws = ws + 16384;        // 8192 floats

    wfft_kernel<<<1, 256, 0, stream>>>(weight, wfft_br);

    // mean path: batch0 row -> re, batch1 row -> im of one packed block
    row_conv2_kernel<<<1, 256, 0, stream>>>(mean_in, mean_out, wfft_br,
                                            nullptr, nullptr);

    // K1: conv along K for every row pair (with s[I]*s[K] scaling) -> X1
    row_conv2_kernel<<<NB * NN / 2, 256, 0, stream>>>(corr_in, corr_out, wfft_br,
                                                      std_in, nullptr);

    // K2: in-place transpose -> X1^T
    dim3 tg(64, 64, NB);
    transpose_inplace_kernel<<<tg, 256, 0, stream>>>(corr_out);

    // K3: conv along I (row pairs of X1^T), in place; extract diag -> var
    row_conv2_kernel<<<NB * NN / 2, 256, 0, stream>>>(corr_out, corr_out, wfft_br,
                                                      nullptr, var_ws);

    std_kernel<<<(NB * NN + 255) / 256, 256, 0, stream>>>(var_ws, std_out,
                                                          rstd_ws, NB * NN);

    // K4: in-place transpose + normalize -> corr_out
    norm_transpose_inplace_kernel<<<tg, 256, 0, stream>>>(corr_out, rstd_ws);
}